// Round 10
// baseline (303.835 us; speedup 1.0000x reference)
//
#include <hip/hip_runtime.h>
#include <hip/hip_bf16.h>
#include <math.h>

#define Tn 100
#define Bn 2048

typedef int v2i __attribute__((ext_vector_type(2)));

__device__ __forceinline__ float sp_f(float x) {
    // jax.nn.softplus(x) = max(x,0) + log1p(exp(-|x|))
    float e = __expf(-fabsf(x));
    return fmaxf(x, 0.f) + __logf(1.f + e);
}
__device__ __forceinline__ float clamp6(float x) {
    return fminf(fmaxf(x, -6.f), 6.f);
}
// DPP cross-lane (pure VALU).
__device__ __forceinline__ float dpp_xor1(float x) {
    return __int_as_float(__builtin_amdgcn_mov_dpp(__float_as_int(x), 0xB1, 0xF, 0xF, 1));
}
__device__ __forceinline__ float dpp_xor2(float x) {
    return __int_as_float(__builtin_amdgcn_mov_dpp(__float_as_int(x), 0x4E, 0xF, 0xF, 1));
}
__device__ __forceinline__ float dpp_hmirror(float x) {   // == xor4 for quad-uniform
    return __int_as_float(__builtin_amdgcn_mov_dpp(__float_as_int(x), 0x141, 0xF, 0xF, 1));
}
__device__ __forceinline__ float dpp_ror8(float x) {      // == xor8 for 8-uniform
    return __int_as_float(__builtin_amdgcn_mov_dpp(__float_as_int(x), 0x128, 0xF, 0xF, 1));
}
template <int OFF>
__device__ __forceinline__ float swz(float x) {
    return __int_as_float(__builtin_amdgcn_ds_swizzle(__float_as_int(x), OFF));
}
// pair-sum of the two 16-rows in each 32-half (== xor16 reduce stage)
__device__ __forceinline__ float xor16_sum(float x) {
#if __has_builtin(__builtin_amdgcn_permlane16_swap)
    v2i r = __builtin_amdgcn_permlane16_swap(__float_as_int(x), __float_as_int(x), false, false);
    return __int_as_float(r[0]) + __int_as_float(r[1]);
#else
    return x + swz<0x401F>(x);
#endif
}
// pair-sum of the two 32-halves (== final xor32 reduce stage)
__device__ __forceinline__ float xor32_sum(float x) {
#if __has_builtin(__builtin_amdgcn_permlane32_swap)
    v2i r = __builtin_amdgcn_permlane32_swap(__float_as_int(x), __float_as_int(x), false, false);
    return __int_as_float(r[0]) + __int_as_float(r[1]);
#else
    return x + __shfl_xor(x, 32);
#endif
}

// h{a,b}[0..29] += v{a,b} * wrow[0..29]; one LDS read stream serves 2 samples.
__device__ __forceinline__ void row2(float* ha, float* hb, const float* wrow,
                                     float va, float vb) {
#pragma unroll
    for (int q = 0; q < 7; ++q) {
        float4 wv = *(const float4*)(wrow + 4 * q);
        ha[4 * q + 0] = fmaf(va, wv.x, ha[4 * q + 0]);
        hb[4 * q + 0] = fmaf(vb, wv.x, hb[4 * q + 0]);
        ha[4 * q + 1] = fmaf(va, wv.y, ha[4 * q + 1]);
        hb[4 * q + 1] = fmaf(vb, wv.y, hb[4 * q + 1]);
        ha[4 * q + 2] = fmaf(va, wv.z, ha[4 * q + 2]);
        hb[4 * q + 2] = fmaf(vb, wv.z, hb[4 * q + 2]);
        ha[4 * q + 3] = fmaf(va, wv.w, ha[4 * q + 3]);
        hb[4 * q + 3] = fmaf(vb, wv.w, hb[4 * q + 3]);
    }
    float2 wt = *(const float2*)(wrow + 28);
    ha[28] = fmaf(va, wt.x, ha[28]);
    hb[28] = fmaf(vb, wt.x, hb[28]);
    ha[29] = fmaf(va, wt.y, ha[29]);
    hb[29] = fmaf(vb, wt.y, hb[29]);
}
// dual dot30: ra = dot(ha,wrow), rb = dot(hb,wrow)
__device__ __forceinline__ void dot30_2(const float* ha, const float* hb,
                                        const float* wrow, float& ra, float& rb) {
    float a0 = 0.f, a1 = 0.f, b0 = 0.f, b1 = 0.f;
#pragma unroll
    for (int q = 0; q < 7; ++q) {
        float4 wv = *(const float4*)(wrow + 4 * q);
        a0 = fmaf(ha[4 * q + 0], wv.x, a0);
        b0 = fmaf(hb[4 * q + 0], wv.x, b0);
        a1 = fmaf(ha[4 * q + 1], wv.y, a1);
        b1 = fmaf(hb[4 * q + 1], wv.y, b1);
        a0 = fmaf(ha[4 * q + 2], wv.z, a0);
        b0 = fmaf(hb[4 * q + 2], wv.z, b0);
        a1 = fmaf(ha[4 * q + 3], wv.w, a1);
        b1 = fmaf(hb[4 * q + 3], wv.w, b1);
    }
    float2 wt = *(const float2*)(wrow + 28);
    a0 = fmaf(ha[28], wt.x, a0);
    b0 = fmaf(hb[28], wt.x, b0);
    a1 = fmaf(ha[29], wt.y, a1);
    b1 = fmaf(hb[29], wt.y, b1);
    ra = a0 + a1; rb = b0 + b1;
}

// ---------------------------------------------------------------- encoder
// M=2 samples/thread; LDS rows padded to stride 32:
// eW1 rows i*32 ; eb1 @4800 ; eW2 rows 4832+j1*32 ; eb2 @5792 ;
// eW3 @5824 (j2*15+j3) ; eb3 @6274.
#define ENC_LOAD2(b0, b1, base)                                               \
    _Pragma("unroll")                                                         \
    for (int i = 0; i < 5; ++i) {                                             \
        b0[i] = *(const float2*)(x0 + (base) + 2 * i);                        \
        b1[i] = *(const float2*)(x1 + (base) + 2 * i);                        \
    }
#define ENC_COMP2(b0, b1, base)                                               \
    _Pragma("unroll")                                                         \
    for (int i = 0; i < 5; ++i) {                                             \
        row2(h1a, h1b, &w[(base + 2 * i) * 32], b0[i].x, b1[i].x);            \
        row2(h1a, h1b, &w[(base + 2 * i + 1) * 32], b0[i].y, b1[i].y);        \
    }

__global__ __launch_bounds__(256) void enc_kernel(
    const float* __restrict__ xs,
    const float* __restrict__ eW1, const float* __restrict__ eb1,
    const float* __restrict__ eW2, const float* __restrict__ eb2,
    const float* __restrict__ eW3, const float* __restrict__ eb3,
    float* __restrict__ ctx, float* __restrict__ qm, float* __restrict__ qs)
{
    __shared__ float w[6292];
    for (int i = threadIdx.x; i < 4500; i += 256) w[(i / 30) * 32 + (i % 30)] = eW1[i];
    if (threadIdx.x < 30) w[4800 + threadIdx.x] = eb1[threadIdx.x];
    for (int i = threadIdx.x; i < 900; i += 256) w[4832 + (i / 30) * 32 + (i % 30)] = eW2[i];
    if (threadIdx.x < 30) w[5792 + threadIdx.x] = eb2[threadIdx.x];
    for (int i = threadIdx.x; i < 450; i += 256) w[5824 + i] = eW3[i];
    if (threadIdx.x < 15) w[6274 + threadIdx.x] = eb3[threadIdx.x];
    __syncthreads();

    int t = threadIdx.x;
    size_t base = (size_t)blockIdx.x * 512;
    size_t s0 = base + t, s1 = base + t + 256;
    const float* x0 = xs + s0 * 150;
    const float* x1 = xs + s1 * 150;

    float h1a[30], h1b[30];
#pragma unroll
    for (int j = 0; j < 30; ++j) { h1a[j] = w[4800 + j]; h1b[j] = h1a[j]; }

    float2 A0[5], A1[5], B0[5], B1[5];
    ENC_LOAD2(A0, A1, 0)
    ENC_LOAD2(B0, B1, 10)
    int fb = 0;
#pragma unroll 1
    for (int it = 0; it < 6; ++it) {
        ENC_COMP2(A0, A1, fb)
        ENC_LOAD2(A0, A1, fb + 20)
        ENC_COMP2(B0, B1, fb + 10)
        ENC_LOAD2(B0, B1, fb + 30)
        fb += 20;
    }
    ENC_COMP2(A0, A1, 120)
    ENC_LOAD2(A0, A1, 140)
    ENC_COMP2(B0, B1, 130)
    ENC_COMP2(A0, A1, 140)

#pragma unroll
    for (int j = 0; j < 30; ++j) { h1a[j] = sp_f(h1a[j]); h1b[j] = sp_f(h1b[j]); }

    float h2a[30], h2b[30];
#pragma unroll
    for (int j = 0; j < 30; ++j) { h2a[j] = w[5792 + j]; h2b[j] = h2a[j]; }
#pragma unroll
    for (int j1 = 0; j1 < 30; ++j1)
        row2(h2a, h2b, &w[4832 + j1 * 32], h1a[j1], h1b[j1]);
#pragma unroll
    for (int j = 0; j < 30; ++j) { h2a[j] = sp_f(h2a[j]); h2b[j] = sp_f(h2b[j]); }

    float oa12 = w[6274 + 12], oa13 = w[6274 + 13], oa14 = w[6274 + 14];
    float ob12 = oa12, ob13 = oa13, ob14 = oa14;
#pragma unroll
    for (int j2 = 0; j2 < 30; ++j2) {
        float w12 = w[5824 + j2 * 15 + 12];
        float w13 = w[5824 + j2 * 15 + 13];
        float w14 = w[5824 + j2 * 15 + 14];
        oa12 = fmaf(h2a[j2], w12, oa12); ob12 = fmaf(h2b[j2], w12, ob12);
        oa13 = fmaf(h2a[j2], w13, oa13); ob13 = fmaf(h2b[j2], w13, ob13);
        oa14 = fmaf(h2a[j2], w14, oa14); ob14 = fmaf(h2b[j2], w14, ob14);
    }
    float* cp0 = ctx + s0 * 3;
    cp0[0] = oa12; cp0[1] = oa13; cp0[2] = oa14;
    float* cp1 = ctx + s1 * 3;
    cp1[0] = ob12; cp1[1] = ob13; cp1[2] = ob14;

    if (blockIdx.x < 4) {   // samples < 2048: tt == 0 -> qz0 stats
        float oa[12], ob[12];
#pragma unroll
        for (int j3 = 0; j3 < 12; ++j3) { oa[j3] = w[6274 + j3]; ob[j3] = oa[j3]; }
#pragma unroll
        for (int j2 = 0; j2 < 30; ++j2) {
            float hva = h2a[j2], hvb = h2b[j2];
#pragma unroll
            for (int j3 = 0; j3 < 12; ++j3) {
                float wv = w[5824 + j2 * 15 + j3];
                oa[j3] = fmaf(hva, wv, oa[j3]);
                ob[j3] = fmaf(hvb, wv, ob[j3]);
            }
        }
#pragma unroll
        for (int d = 0; d < 6; ++d) {
            qm[s0 * 6 + d] = oa[d]; qs[s0 * 6 + d] = oa[6 + d];
            qm[s1 * 6 + d] = ob[d]; qs[s1 * 6 + d] = ob[6 + d];
        }
    }
}

// ------------------------------------------------------------------- SDE scan
// 3-wave role split: block = 192 threads per chain, grid = 2048
// -> 24 waves/CU (8 blocks x 5KB LDS). Wave F (wid 0): f-network, lanes 0-29
// one column each, full-wave DPP allreduce. Wave H (wid 1): h-network, same.
// Wave G (wid 2): g-network on 8-lane dim groups + path integrand + KL.
// One converged barrier per step; every wave re-derives z from LDS quads.
__global__ __launch_bounds__(192, 6) void scan_kernel(
    const float* __restrict__ ts, const float* __restrict__ dWall,
    const float* __restrict__ fW1, const float* __restrict__ fb1,
    const float* __restrict__ fW2, const float* __restrict__ fb2,
    const float* __restrict__ hW1, const float* __restrict__ hb1,
    const float* __restrict__ hW2, const float* __restrict__ hb2,
    const float* __restrict__ gW1, const float* __restrict__ gb1,
    const float* __restrict__ gW2, const float* __restrict__ gb2,
    const float* __restrict__ ctx,
    const float* __restrict__ qm, const float* __restrict__ qs,
    const float* __restrict__ eps0, const float* __restrict__ pm,
    const float* __restrict__ ps,
    float* __restrict__ zsb, float* __restrict__ acc)
{
    int tid = threadIdx.x;
    int lane = tid & 63;
    int wid = tid >> 6;               // 0=F, 1=H, 2=G
    int b = blockIdx.x;

    __shared__ float sRec[99 * 12];   // [0..5]=dW, [6..8]=ctx(k+1), [9]=t, [10]=dt
    __shared__ float exF[2][8];       // fvv[0..5]
    __shared__ float exH[2][8];       // hvv[0..5]
    __shared__ float exG[2][16];      // {g,rg} pairs

    // ---- bulk staging (192 threads) -----------------------------------
    for (int i = tid; i < 99 * 3; i += 192) {
        int k = i / 3, e = i % 3;
        float2 v = *(const float2*)(dWall + ((size_t)k * Bn + b) * 6 + e * 2);
        *(float2*)&sRec[k * 12 + e * 2] = v;
    }
    for (int i = tid; i < 99 * 3; i += 192) {
        int k = i / 3, e = i % 3;
        sRec[k * 12 + 6 + e] = ctx[((size_t)(k + 1) * Bn + b) * 3 + e];
    }
    for (int i = tid; i < 99; i += 192) {
        float t0 = ts[i], t1 = ts[i + 1];
        sRec[i * 12 + 9]  = t0;
        sRec[i * 12 + 10] = t1 - t0;
        sRec[i * 12 + 11] = 0.f;
    }

    // ---- z0 (identical on all lanes; uniform broadcast loads) ---------
    float z[6];
#pragma unroll
    for (int d = 0; d < 6; ++d) {
        float m = qm[b * 6 + d];
        float sq = __expf(clamp6(qs[b * 6 + d]));
        z[d] = fmaf(sq, eps0[b * 6 + d], m);
    }
    if (tid == 0) {
        float* zp = zsb + (size_t)b * 6;
        *(float2*)(zp)     = make_float2(z[0], z[1]);
        *(float2*)(zp + 2) = make_float2(z[2], z[3]);
        *(float2*)(zp + 4) = make_float2(z[4], z[5]);
    }
    if (tid == 64) {                                   // chain KL partial
        float klsum = 0.f;
#pragma unroll
        for (int d = 0; d < 6; ++d) {
            float m = qm[b * 6 + d];
            float sq = __expf(clamp6(qs[b * 6 + d]));
            float spz = __expf(clamp6(ps[d]));
            float dm = m - pm[d];
            klsum += __logf(spz / sq) + (sq * sq + dm * dm) / (2.f * spz * spz) - 0.5f;
        }
        atomicAdd(&acc[1], klsum);
    }

    // ---- per-wave weights ---------------------------------------------
    float wl1[10], b1w, wl2[6], bias2[6];      // F / H waves
    float gwa[4], gwb[4], gw2v[4], gbb[4], gb2v;   // G wave
    int dL = 0;
    if (wid == 0) {
        int jc = (lane < 30) ? lane : 29;
        bool jvalid = (lane < 30);
#pragma unroll
        for (int i = 0; i < 10; ++i) wl1[i] = fW1[i * 30 + jc];
        b1w = fb1[jc];
#pragma unroll
        for (int d = 0; d < 6; ++d) {
            wl2[d] = jvalid ? fW2[jc * 6 + d] : 0.f;
            bias2[d] = fb2[d];
        }
    } else if (wid == 1) {
        int jc = (lane < 30) ? lane : 29;
        bool jvalid = (lane < 30);
#pragma unroll
        for (int i = 0; i < 7; ++i) wl1[i] = hW1[i * 30 + jc];
#pragma unroll
        for (int i = 7; i < 10; ++i) wl1[i] = 0.f;
        b1w = hb1[jc];
#pragma unroll
        for (int d = 0; d < 6; ++d) {
            wl2[d] = jvalid ? hW2[jc * 6 + d] : 0.f;
            bias2[d] = hb2[d];
        }
    } else {
        int dL8 = lane >> 3;
        dL = (dL8 < 6) ? dL8 : 0;
        int s = lane & 7;
#pragma unroll
        for (int u = 0; u < 4; ++u) {
            int jj = s + 8 * u;
            bool ok = (dL8 < 6) && (jj < 30);
            gwa[u]  = ok ? gW1[dL * 60 + jj] : 0.f;        // t coeff
            gwb[u]  = ok ? gW1[dL * 60 + 30 + jj] : 0.f;   // z coeff
            gw2v[u] = ok ? gW2[dL * 30 + jj] : 0.f;
            gbb[u]  = ok ? gb1[dL * 30 + jj] : 0.f;
        }
        gb2v = gb2[dL];
    }

    __syncthreads();

    float pacc = 0.f;

    for (int k = 0; k < Tn - 1; ++k) {
        int kb = k & 1;
        float4 r0 = *(float4*)&sRec[k * 12];       // dw0..3
        float4 r1 = *(float4*)&sRec[k * 12 + 4];   // dw4,dw5,c0,c1
        float4 r2 = *(float4*)&sRec[k * 12 + 8];   // c2,t,dt,pad
        float t = r2.y, dt = r2.z;

        if (wid < 2) {
            // ---- F or H hidden: one column per lane -------------------
            float a = fmaf(t, wl1[0], b1w);
#pragma unroll
            for (int i = 0; i < 6; ++i) a = fmaf(z[i], wl1[1 + i], a);
            a = fmaf(r1.z, wl1[7], a);
            a = fmaf(r1.w, wl1[8], a);
            a = fmaf(r2.x, wl1[9], a);
            float hid = sp_f(a);

            float pp[6];
#pragma unroll
            for (int d = 0; d < 6; ++d) pp[d] = hid * wl2[d];
#pragma unroll
            for (int d = 0; d < 6; ++d) pp[d] += dpp_xor1(pp[d]);
#pragma unroll
            for (int d = 0; d < 6; ++d) pp[d] += dpp_xor2(pp[d]);
#pragma unroll
            for (int d = 0; d < 6; ++d) pp[d] += dpp_hmirror(pp[d]);
#pragma unroll
            for (int d = 0; d < 6; ++d) pp[d] += dpp_ror8(pp[d]);
#pragma unroll
            for (int d = 0; d < 6; ++d) pp[d] = xor16_sum(pp[d]);
#pragma unroll
            for (int d = 0; d < 6; ++d) pp[d] = xor32_sum(pp[d]) + bias2[d];
            if (lane == 0) {
                float* ex = (wid == 0) ? &exF[kb][0] : &exH[kb][0];
                *(float4*)(ex)     = make_float4(pp[0], pp[1], pp[2], pp[3]);
                *(float2*)(ex + 4) = make_float2(pp[4], pp[5]);
            }
        } else {
            // ---- G: own-dim z, 4 units/lane, 8-lane-group reduce ------
            float zq = z[0];
            zq = (dL == 1) ? z[1] : zq;
            zq = (dL == 2) ? z[2] : zq;
            zq = (dL == 3) ? z[3] : zq;
            zq = (dL == 4) ? z[4] : zq;
            zq = (dL == 5) ? z[5] : zq;
            float ga = 0.f;
#pragma unroll
            for (int u = 0; u < 4; ++u) {
                float pre = fmaf(t, gwa[u], gbb[u]);
                pre = fmaf(zq, gwb[u], pre);
                ga = fmaf(sp_f(pre), gw2v[u], ga);
            }
            ga += dpp_xor1(ga);
            ga += dpp_xor2(ga);
            ga += dpp_hmirror(ga);
            float gacc = ga + gb2v;
            float e = __expf(-gacc);
            float rg = 1.f + e;                          // = 1/sigmoid(gacc)
            float gval = __builtin_amdgcn_rcpf(rg);
            if ((lane & 7) == 0 && (lane >> 3) < 6)
                *(float2*)&exG[kb][2 * dL] = make_float2(gval, rg);
        }

        __syncthreads();   // single converged barrier per step

        // ---- converged tail: all three waves update z identically -----
        float4 fA = *(float4*)&exF[kb][0];
        float2 fB = *(float2*)&exF[kb][4];
        float4 hA = *(float4*)&exH[kb][0];
        float2 hB = *(float2*)&exH[kb][4];
        float4 e01 = *(float4*)&exG[kb][0];
        float4 e23 = *(float4*)&exG[kb][4];
        float4 e45 = *(float4*)&exG[kb][8];
        float fvv[6] = { fA.x, fA.y, fA.z, fA.w, fB.x, fB.y };
        float hvv[6] = { hA.x, hA.y, hA.z, hA.w, hB.x, hB.y };
        float gl[6]  = { e01.x, e01.z, e23.x, e23.z, e45.x, e45.z };

        if (wid == 2) {
            float rgv[6] = { e01.y, e01.w, e23.y, e23.w, e45.y, e45.w };
            float s2 = 0.f;
#pragma unroll
            for (int d = 0; d < 6; ++d) {
                float u = (fvv[d] - hvv[d]) * rgv[d];
                s2 = fmaf(u, u, s2);
            }
            pacc = fmaf(0.5f * dt, s2, pacc);
        }

        float dwv[6] = { r0.x, r0.y, r0.z, r0.w, r1.x, r1.y };
#pragma unroll
        for (int d = 0; d < 6; ++d)
            z[d] = fmaf(gl[d], dwv[d], fmaf(fvv[d], dt, z[d]));

        if (tid == 0) {
            float* zp = zsb + ((size_t)(k + 1) * Bn + b) * 6;
            *(float2*)(zp)     = make_float2(z[0], z[1]);
            *(float2*)(zp + 2) = make_float2(z[2], z[3]);
            *(float2*)(zp + 4) = make_float2(z[4], z[5]);
        }
    }
    if (tid == 128) atomicAdd(&acc[2], pacc);   // pacc uniform on wave G
}

// ------------------------------------------------------ decoder + likelihood
// M=2 samples/thread; LDS layout: dcW1 rows i*32 ; dcb1 @192 ;
// dcW2 rows 224+j1*32 ; dcb2 @1184 ; dcW3T rows 1216+j3*32 ; dcb3 @4416.
#define DEC_TLOAD(b0, b1, base)                                               \
    _Pragma("unroll")                                                         \
    for (int i = 0; i < 5; ++i) {                                             \
        b0[i] = *(const float2*)(tg0 + (base) + 2 * i);                       \
        b1[i] = *(const float2*)(tg1 + (base) + 2 * i);                       \
    }
#define DEC_LCOMP(b0, b1, base)                                               \
    _Pragma("unroll")                                                         \
    for (int i = 0; i < 10; ++i) {                                            \
        int ff = (base) + i;                                                  \
        float dma, dmb, dla, dlb;                                             \
        dot30_2(h2a, h2b, &w[1216 + ff * 32], dma, dmb);                      \
        dot30_2(h2a, h2b, &w[1216 + (50 + ff) * 32], dla, dlb);               \
        float xma = w[4416 + ff] + dma, xmb = w[4416 + ff] + dmb;             \
        float cla = clamp6(w[4416 + 50 + ff] + dla);                          \
        float clb = clamp6(w[4416 + 50 + ff] + dlb);                          \
        float tva = (i & 1) ? b0[i >> 1].y : b0[i >> 1].x;                    \
        float tvb = (i & 1) ? b1[i >> 1].y : b1[i >> 1].x;                    \
        float ua = (tva - xma) * __expf(-cla);                                \
        float ub = (tvb - xmb) * __expf(-clb);                                \
        lpa += -0.5f * ua * ua - cla - 0.91893853320467274f;                  \
        lpb += -0.5f * ub * ub - clb - 0.91893853320467274f;                  \
    }

__global__ __launch_bounds__(256) void dec_kernel(
    const float* __restrict__ zsb, const float* __restrict__ xs,
    const float* __restrict__ dcW1, const float* __restrict__ dcb1,
    const float* __restrict__ dcW2, const float* __restrict__ dcb2,
    const float* __restrict__ dcW3, const float* __restrict__ dcb3,
    float* __restrict__ acc)
{
    __shared__ float w[4516];
    for (int i = threadIdx.x; i < 180; i += 256) w[(i / 30) * 32 + (i % 30)] = dcW1[i];
    if (threadIdx.x < 30) w[192 + threadIdx.x] = dcb1[threadIdx.x];
    for (int i = threadIdx.x; i < 900; i += 256) w[224 + (i / 30) * 32 + (i % 30)] = dcW2[i];
    if (threadIdx.x < 30) w[1184 + threadIdx.x] = dcb2[threadIdx.x];
    for (int i = threadIdx.x; i < 3000; i += 256) {
        int j2 = i / 100, j3 = i % 100;
        w[1216 + j3 * 32 + j2] = dcW3[i];
    }
    for (int i = threadIdx.x; i < 100; i += 256) w[4416 + i] = dcb3[i];
    __syncthreads();

    int t = threadIdx.x;
    size_t base = (size_t)blockIdx.x * 512;
    size_t s0 = base + t, s1 = base + t + 256;

    float za[6], zb[6];
    {
        const float* zp0 = zsb + s0 * 6;
        const float* zp1 = zsb + s1 * 6;
#pragma unroll
        for (int i = 0; i < 3; ++i) {
            float2 v0 = *(const float2*)(zp0 + 2 * i);
            float2 v1 = *(const float2*)(zp1 + 2 * i);
            za[2 * i] = v0.x; za[2 * i + 1] = v0.y;
            zb[2 * i] = v1.x; zb[2 * i + 1] = v1.y;
        }
    }

    float h1a[30], h1b[30];
#pragma unroll
    for (int j = 0; j < 30; ++j) { h1a[j] = w[192 + j]; h1b[j] = h1a[j]; }
#pragma unroll
    for (int i = 0; i < 6; ++i) row2(h1a, h1b, &w[i * 32], za[i], zb[i]);
#pragma unroll
    for (int j = 0; j < 30; ++j) { h1a[j] = sp_f(h1a[j]); h1b[j] = sp_f(h1b[j]); }

    float h2a[30], h2b[30];
#pragma unroll
    for (int j = 0; j < 30; ++j) { h2a[j] = w[1184 + j]; h2b[j] = h2a[j]; }
#pragma unroll
    for (int j1 = 0; j1 < 30; ++j1)
        row2(h2a, h2b, &w[224 + j1 * 32], h1a[j1], h1b[j1]);
#pragma unroll
    for (int j = 0; j < 30; ++j) { h2a[j] = sp_f(h2a[j]); h2b[j] = sp_f(h2b[j]); }

    const float* tg0 = xs + s0 * 150 + 100;   // xs[:,:,-1,:]
    const float* tg1 = xs + s1 * 150 + 100;
    float lpa = 0.f, lpb = 0.f;
    float2 TA0[5], TA1[5], TB0[5], TB1[5];
    DEC_TLOAD(TA0, TA1, 0)
    DEC_TLOAD(TB0, TB1, 10)
    DEC_LCOMP(TA0, TA1, 0)
    DEC_TLOAD(TA0, TA1, 20)
    DEC_LCOMP(TB0, TB1, 10)
    DEC_TLOAD(TB0, TB1, 30)
    DEC_LCOMP(TA0, TA1, 20)
    DEC_TLOAD(TA0, TA1, 40)
    DEC_LCOMP(TB0, TB1, 30)
    DEC_LCOMP(TA0, TA1, 40)

    float lpacc = lpa + lpb;
#pragma unroll
    for (int mm = 1; mm <= 32; mm <<= 1) lpacc += __shfl_xor(lpacc, mm);
    __shared__ float red[4];
    if ((threadIdx.x & 63) == 0) red[threadIdx.x >> 6] = lpacc;
    __syncthreads();
    if (threadIdx.x == 0) atomicAdd(&acc[0], red[0] + red[1] + red[2] + red[3]);
}

__global__ void final_kernel(const float* __restrict__ acc, float* __restrict__ out)
{
    out[0] = acc[0] * (1.f / (float)Bn);
    out[1] = (acc[1] + acc[2]) * (1.f / (float)Bn);
}

// --------------------------------------------------------------------- launch
extern "C" void kernel_launch(void* const* d_in, const int* in_sizes, int n_in,
                              void* d_out, int out_size, void* d_ws, size_t ws_size,
                              hipStream_t stream)
{
    const float* xs   = (const float*)d_in[0];
    const float* ts   = (const float*)d_in[1];
    const float* eps0 = (const float*)d_in[2];
    const float* dW   = (const float*)d_in[3];
    const float* eW1  = (const float*)d_in[4];
    const float* eb1  = (const float*)d_in[5];
    const float* eW2  = (const float*)d_in[6];
    const float* eb2  = (const float*)d_in[7];
    const float* eW3  = (const float*)d_in[8];
    const float* eb3  = (const float*)d_in[9];
    const float* dcW1 = (const float*)d_in[10];
    const float* dcb1 = (const float*)d_in[11];
    const float* dcW2 = (const float*)d_in[12];
    const float* dcb2 = (const float*)d_in[13];
    const float* dcW3 = (const float*)d_in[14];
    const float* dcb3 = (const float*)d_in[15];
    const float* fW1  = (const float*)d_in[16];
    const float* fb1  = (const float*)d_in[17];
    const float* fW2  = (const float*)d_in[18];
    const float* fb2  = (const float*)d_in[19];
    const float* hW1  = (const float*)d_in[20];
    const float* hb1  = (const float*)d_in[21];
    const float* hW2  = (const float*)d_in[22];
    const float* hb2  = (const float*)d_in[23];
    const float* gW1  = (const float*)d_in[24];
    const float* gb1  = (const float*)d_in[25];
    const float* gW2  = (const float*)d_in[26];
    const float* gb2  = (const float*)d_in[27];
    const float* pm   = (const float*)d_in[28];
    const float* ps   = (const float*)d_in[29];

    float* ws  = (float*)d_ws;
    float* acc = ws;                    // [0]=S_lp, [1]=S_kl, [2]=S_path
    float* ctx = ws + 16;               // T*B*3 = 614400
    float* qm  = ctx + 614400;          // B*6
    float* qs  = qm + 12288;            // B*6
    float* zs  = qs + 12288;            // T*B*6 = 1228800
    float* out = (float*)d_out;

    hipMemsetAsync(acc, 0, 16 * sizeof(float), stream);
    enc_kernel<<<400, 256, 0, stream>>>(xs, eW1, eb1, eW2, eb2, eW3, eb3, ctx, qm, qs);
    scan_kernel<<<2048, 192, 0, stream>>>(ts, dW, fW1, fb1, fW2, fb2, hW1, hb1,
                                          hW2, hb2, gW1, gb1, gW2, gb2, ctx,
                                          qm, qs, eps0, pm, ps, zs, acc);
    dec_kernel<<<400, 256, 0, stream>>>(zs, xs, dcW1, dcb1, dcW2, dcb2, dcW3, dcb3, acc);
    final_kernel<<<1, 1, 0, stream>>>(acc, out);
}

// Round 11
// 253.485 us; speedup vs baseline: 1.1986x; 1.1986x over previous
//
#include <hip/hip_runtime.h>
#include <hip/hip_bf16.h>
#include <math.h>

#define Tn 100
#define Bn 2048

typedef int v2i __attribute__((ext_vector_type(2)));

__device__ __forceinline__ float sp_f(float x) {
    // jax.nn.softplus(x) = max(x,0) + log1p(exp(-|x|))
    float e = __expf(-fabsf(x));
    return fmaxf(x, 0.f) + __logf(1.f + e);
}
__device__ __forceinline__ float clamp6(float x) {
    return fminf(fmaxf(x, -6.f), 6.f);
}
// DPP cross-lane (pure VALU).
__device__ __forceinline__ float dpp_xor1(float x) {
    return __int_as_float(__builtin_amdgcn_mov_dpp(__float_as_int(x), 0xB1, 0xF, 0xF, 1));
}
__device__ __forceinline__ float dpp_xor2(float x) {
    return __int_as_float(__builtin_amdgcn_mov_dpp(__float_as_int(x), 0x4E, 0xF, 0xF, 1));
}
__device__ __forceinline__ float dpp_hmirror(float x) {   // == xor4 for quad-uniform
    return __int_as_float(__builtin_amdgcn_mov_dpp(__float_as_int(x), 0x141, 0xF, 0xF, 1));
}
__device__ __forceinline__ float dpp_ror8(float x) {      // == xor8 for 8-uniform
    return __int_as_float(__builtin_amdgcn_mov_dpp(__float_as_int(x), 0x128, 0xF, 0xF, 1));
}
template <int OFF>
__device__ __forceinline__ float swz(float x) {
    return __int_as_float(__builtin_amdgcn_ds_swizzle(__float_as_int(x), OFF));
}
// pair-sum of the two 16-rows in each 32-half (== xor16 reduce stage)
__device__ __forceinline__ float xor16_sum(float x) {
#if __has_builtin(__builtin_amdgcn_permlane16_swap)
    v2i r = __builtin_amdgcn_permlane16_swap(__float_as_int(x), __float_as_int(x), false, false);
    return __int_as_float(r[0]) + __int_as_float(r[1]);
#else
    return x + swz<0x401F>(x);
#endif
}
// value of lane (tid^32): direction-agnostic via r0+r1-own.
__device__ __forceinline__ float other_half(float x) {
#if __has_builtin(__builtin_amdgcn_permlane32_swap)
    v2i r = __builtin_amdgcn_permlane32_swap(__float_as_int(x), __float_as_int(x), false, false);
    return (__int_as_float(r[0]) + __int_as_float(r[1])) - x;
#else
    return __shfl_xor(x, 32);
#endif
}

// h{a,b}[0..29] += v{a,b} * wrow[0..29]; one LDS read stream serves 2 samples.
__device__ __forceinline__ void row2(float* ha, float* hb, const float* wrow,
                                     float va, float vb) {
#pragma unroll
    for (int q = 0; q < 7; ++q) {
        float4 wv = *(const float4*)(wrow + 4 * q);
        ha[4 * q + 0] = fmaf(va, wv.x, ha[4 * q + 0]);
        hb[4 * q + 0] = fmaf(vb, wv.x, hb[4 * q + 0]);
        ha[4 * q + 1] = fmaf(va, wv.y, ha[4 * q + 1]);
        hb[4 * q + 1] = fmaf(vb, wv.y, hb[4 * q + 1]);
        ha[4 * q + 2] = fmaf(va, wv.z, ha[4 * q + 2]);
        hb[4 * q + 2] = fmaf(vb, wv.z, hb[4 * q + 2]);
        ha[4 * q + 3] = fmaf(va, wv.w, ha[4 * q + 3]);
        hb[4 * q + 3] = fmaf(vb, wv.w, hb[4 * q + 3]);
    }
    float2 wt = *(const float2*)(wrow + 28);
    ha[28] = fmaf(va, wt.x, ha[28]);
    hb[28] = fmaf(vb, wt.x, hb[28]);
    ha[29] = fmaf(va, wt.y, ha[29]);
    hb[29] = fmaf(vb, wt.y, hb[29]);
}
// dual dot30: ra = dot(ha,wrow), rb = dot(hb,wrow)
__device__ __forceinline__ void dot30_2(const float* ha, const float* hb,
                                        const float* wrow, float& ra, float& rb) {
    float a0 = 0.f, a1 = 0.f, b0 = 0.f, b1 = 0.f;
#pragma unroll
    for (int q = 0; q < 7; ++q) {
        float4 wv = *(const float4*)(wrow + 4 * q);
        a0 = fmaf(ha[4 * q + 0], wv.x, a0);
        b0 = fmaf(hb[4 * q + 0], wv.x, b0);
        a1 = fmaf(ha[4 * q + 1], wv.y, a1);
        b1 = fmaf(hb[4 * q + 1], wv.y, b1);
        a0 = fmaf(ha[4 * q + 2], wv.z, a0);
        b0 = fmaf(hb[4 * q + 2], wv.z, b0);
        a1 = fmaf(ha[4 * q + 3], wv.w, a1);
        b1 = fmaf(hb[4 * q + 3], wv.w, b1);
    }
    float2 wt = *(const float2*)(wrow + 28);
    a0 = fmaf(ha[28], wt.x, a0);
    b0 = fmaf(hb[28], wt.x, b0);
    a1 = fmaf(ha[29], wt.y, a1);
    b1 = fmaf(hb[29], wt.y, b1);
    ra = a0 + a1; rb = b0 + b1;
}

// ---------------------------------------------------------------- encoder
// M=2 samples/thread; LDS rows padded to stride 32:
// eW1 rows i*32 ; eb1 @4800 ; eW2 rows 4832+j1*32 ; eb2 @5792 ;
// eW3 @5824 (j2*15+j3) ; eb3 @6274.
#define ENC_LOAD2(b0, b1, base)                                               \
    _Pragma("unroll")                                                         \
    for (int i = 0; i < 5; ++i) {                                             \
        b0[i] = *(const float2*)(x0 + (base) + 2 * i);                        \
        b1[i] = *(const float2*)(x1 + (base) + 2 * i);                        \
    }
#define ENC_COMP2(b0, b1, base)                                               \
    _Pragma("unroll")                                                         \
    for (int i = 0; i < 5; ++i) {                                             \
        row2(h1a, h1b, &w[(base + 2 * i) * 32], b0[i].x, b1[i].x);            \
        row2(h1a, h1b, &w[(base + 2 * i + 1) * 32], b0[i].y, b1[i].y);        \
    }

__global__ __launch_bounds__(256) void enc_kernel(
    const float* __restrict__ xs,
    const float* __restrict__ eW1, const float* __restrict__ eb1,
    const float* __restrict__ eW2, const float* __restrict__ eb2,
    const float* __restrict__ eW3, const float* __restrict__ eb3,
    float* __restrict__ ctx, float* __restrict__ qm, float* __restrict__ qs)
{
    __shared__ float w[6292];
    for (int i = threadIdx.x; i < 4500; i += 256) w[(i / 30) * 32 + (i % 30)] = eW1[i];
    if (threadIdx.x < 30) w[4800 + threadIdx.x] = eb1[threadIdx.x];
    for (int i = threadIdx.x; i < 900; i += 256) w[4832 + (i / 30) * 32 + (i % 30)] = eW2[i];
    if (threadIdx.x < 30) w[5792 + threadIdx.x] = eb2[threadIdx.x];
    for (int i = threadIdx.x; i < 450; i += 256) w[5824 + i] = eW3[i];
    if (threadIdx.x < 15) w[6274 + threadIdx.x] = eb3[threadIdx.x];
    __syncthreads();

    int t = threadIdx.x;
    size_t base = (size_t)blockIdx.x * 512;
    size_t s0 = base + t, s1 = base + t + 256;
    const float* x0 = xs + s0 * 150;
    const float* x1 = xs + s1 * 150;

    float h1a[30], h1b[30];
#pragma unroll
    for (int j = 0; j < 30; ++j) { h1a[j] = w[4800 + j]; h1b[j] = h1a[j]; }

    float2 A0[5], A1[5], B0[5], B1[5];
    ENC_LOAD2(A0, A1, 0)
    ENC_LOAD2(B0, B1, 10)
    int fb = 0;
#pragma unroll 1
    for (int it = 0; it < 6; ++it) {
        ENC_COMP2(A0, A1, fb)
        ENC_LOAD2(A0, A1, fb + 20)
        ENC_COMP2(B0, B1, fb + 10)
        ENC_LOAD2(B0, B1, fb + 30)
        fb += 20;
    }
    ENC_COMP2(A0, A1, 120)
    ENC_LOAD2(A0, A1, 140)
    ENC_COMP2(B0, B1, 130)
    ENC_COMP2(A0, A1, 140)

#pragma unroll
    for (int j = 0; j < 30; ++j) { h1a[j] = sp_f(h1a[j]); h1b[j] = sp_f(h1b[j]); }

    float h2a[30], h2b[30];
#pragma unroll
    for (int j = 0; j < 30; ++j) { h2a[j] = w[5792 + j]; h2b[j] = h2a[j]; }
#pragma unroll
    for (int j1 = 0; j1 < 30; ++j1)
        row2(h2a, h2b, &w[4832 + j1 * 32], h1a[j1], h1b[j1]);
#pragma unroll
    for (int j = 0; j < 30; ++j) { h2a[j] = sp_f(h2a[j]); h2b[j] = sp_f(h2b[j]); }

    float oa12 = w[6274 + 12], oa13 = w[6274 + 13], oa14 = w[6274 + 14];
    float ob12 = oa12, ob13 = oa13, ob14 = oa14;
#pragma unroll
    for (int j2 = 0; j2 < 30; ++j2) {
        float w12 = w[5824 + j2 * 15 + 12];
        float w13 = w[5824 + j2 * 15 + 13];
        float w14 = w[5824 + j2 * 15 + 14];
        oa12 = fmaf(h2a[j2], w12, oa12); ob12 = fmaf(h2b[j2], w12, ob12);
        oa13 = fmaf(h2a[j2], w13, oa13); ob13 = fmaf(h2b[j2], w13, ob13);
        oa14 = fmaf(h2a[j2], w14, oa14); ob14 = fmaf(h2b[j2], w14, ob14);
    }
    float* cp0 = ctx + s0 * 3;
    cp0[0] = oa12; cp0[1] = oa13; cp0[2] = oa14;
    float* cp1 = ctx + s1 * 3;
    cp1[0] = ob12; cp1[1] = ob13; cp1[2] = ob14;

    if (blockIdx.x < 4) {   // samples < 2048: tt == 0 -> qz0 stats
        float oa[12], ob[12];
#pragma unroll
        for (int j3 = 0; j3 < 12; ++j3) { oa[j3] = w[6274 + j3]; ob[j3] = oa[j3]; }
#pragma unroll
        for (int j2 = 0; j2 < 30; ++j2) {
            float hva = h2a[j2], hvb = h2b[j2];
#pragma unroll
            for (int j3 = 0; j3 < 12; ++j3) {
                float wv = w[5824 + j2 * 15 + j3];
                oa[j3] = fmaf(hva, wv, oa[j3]);
                ob[j3] = fmaf(hvb, wv, ob[j3]);
            }
        }
#pragma unroll
        for (int d = 0; d < 6; ++d) {
            qm[s0 * 6 + d] = oa[d]; qs[s0 * 6 + d] = oa[6 + d];
            qm[s1 * 6 + d] = ob[d]; qs[s1 * 6 + d] = ob[6 + d];
        }
    }
}

// ------------------------------------------------------------------- SDE scan
// 2-wave split with ASYMMETRIC SLIM TAILS. Block = 128 thr per chain,
// grid = 2048 (16 waves/CU). Wave A: f (lanes 0-31) + h (lanes 32-63)
// columns, full reduce; keeps full z[6]; tail uses OWN registers + gl from
// LDS. Wave B: g on 8-lane dim groups; keeps ONLY z[dL]; tail reads 3
// scalars. One converged barrier per step, double-buffered exchange.
// sRec record: [0..5]=dW, [6..8]=ctx(k+1), [9]=pad, [10]=t, [11]=dt.
__global__ __launch_bounds__(128, 4) void scan_kernel(
    const float* __restrict__ ts, const float* __restrict__ dWall,
    const float* __restrict__ fW1, const float* __restrict__ fb1,
    const float* __restrict__ fW2, const float* __restrict__ fb2,
    const float* __restrict__ hW1, const float* __restrict__ hb1,
    const float* __restrict__ hW2, const float* __restrict__ hb2,
    const float* __restrict__ gW1, const float* __restrict__ gb1,
    const float* __restrict__ gW2, const float* __restrict__ gb2,
    const float* __restrict__ ctx,
    const float* __restrict__ qm, const float* __restrict__ qs,
    const float* __restrict__ eps0, const float* __restrict__ pm,
    const float* __restrict__ ps,
    float* __restrict__ zsb, float* __restrict__ acc)
{
    int tid = threadIdx.x;
    int lane = tid & 63;
    int b = blockIdx.x;
    bool isA = tid < 64;

    __shared__ float sRec[99 * 12];
    __shared__ float exF[2][12];      // [0..5]=fvv, [6..11]=dfh
    __shared__ float exG[2][8];       // [0..5]=g

    // ---- bulk staging (128 threads) -----------------------------------
    for (int i = tid; i < 99 * 3; i += 128) {
        int k = i / 3, e = i % 3;
        float2 v = *(const float2*)(dWall + ((size_t)k * Bn + b) * 6 + e * 2);
        *(float2*)&sRec[k * 12 + e * 2] = v;
    }
    for (int i = tid; i < 99 * 3; i += 128) {
        int k = i / 3, e = i % 3;
        sRec[k * 12 + 6 + e] = ctx[((size_t)(k + 1) * Bn + b) * 3 + e];
    }
    for (int i = tid; i < 99; i += 128) {
        float t0 = ts[i], t1 = ts[i + 1];
        sRec[i * 12 + 9]  = 0.f;
        sRec[i * 12 + 10] = t0;
        sRec[i * 12 + 11] = t1 - t0;
    }

    // ---- per-wave state & weights -------------------------------------
    float z[6];                                  // wave A full state
    float zq = 0.f;                              // wave B own-dim state
    float wl1[10], b1w, wl2[6], fb2v[6], hb2v[6];
    float gwa[4], gwb[4], gw2v[4], gbb[4], gb2v = 0.f, wselq = 0.f;
    int dL = 0;

    if (isA) {
        bool lower = lane < 32;
        int j = lane & 31;
        int jc = (j < 30) ? j : 29;
        bool jvalid = (j < 30);
#pragma unroll
        for (int i = 0; i < 10; ++i)
            wl1[i] = lower ? fW1[i * 30 + jc] : (i < 7 ? hW1[i * 30 + jc] : 0.f);
        b1w = lower ? fb1[jc] : hb1[jc];
#pragma unroll
        for (int d = 0; d < 6; ++d)
            wl2[d] = jvalid ? (lower ? fW2[jc * 6 + d] : hW2[jc * 6 + d]) : 0.f;
#pragma unroll
        for (int d = 0; d < 6; ++d) { fb2v[d] = fb2[d]; hb2v[d] = hb2[d]; }
        // full z0
#pragma unroll
        for (int d = 0; d < 6; ++d) {
            float m = qm[b * 6 + d];
            float sq = __expf(clamp6(qs[b * 6 + d]));
            z[d] = fmaf(sq, eps0[b * 6 + d], m);
        }
        if (tid == 0) {
            float* zp = zsb + (size_t)b * 6;
            *(float2*)(zp)     = make_float2(z[0], z[1]);
            *(float2*)(zp + 2) = make_float2(z[2], z[3]);
            *(float2*)(zp + 4) = make_float2(z[4], z[5]);
        }
    } else {
        int dL8 = lane >> 3;
        dL = (dL8 < 6) ? dL8 : 0;
        wselq = (dL8 < 6) ? 0.0625f : 0.f;       // 0.5/8 lanes per dim
        int s = lane & 7;
#pragma unroll
        for (int u = 0; u < 4; ++u) {
            int jj = s + 8 * u;
            bool ok = (dL8 < 6) && (jj < 30);
            gwa[u]  = ok ? gW1[dL * 60 + jj] : 0.f;        // t coeff
            gwb[u]  = ok ? gW1[dL * 60 + 30 + jj] : 0.f;   // z coeff
            gw2v[u] = ok ? gW2[dL * 30 + jj] : 0.f;
            gbb[u]  = ok ? gb1[dL * 30 + jj] : 0.f;
        }
        gb2v = gb2[dL];
        // own-dim z0
        {
            float m = qm[b * 6 + dL];
            float sq = __expf(clamp6(qs[b * 6 + dL]));
            zq = fmaf(sq, eps0[b * 6 + dL], m);
        }
        if (tid == 64) {                                   // chain KL partial
            float klsum = 0.f;
#pragma unroll
            for (int d = 0; d < 6; ++d) {
                float m = qm[b * 6 + d];
                float sq = __expf(clamp6(qs[b * 6 + d]));
                float spz = __expf(clamp6(ps[d]));
                float dm = m - pm[d];
                klsum += __logf(spz / sq) + (sq * sq + dm * dm) / (2.f * spz * spz) - 0.5f;
            }
            atomicAdd(&acc[1], klsum);
        }
    }

    __syncthreads();

    float pacc = 0.f;

    for (int k = 0; k < Tn - 1; ++k) {
        int kb = k & 1;

        if (isA) {
            float4 r0 = *(float4*)&sRec[k * 12];       // dw0..3
            float4 r1 = *(float4*)&sRec[k * 12 + 4];   // dw4,dw5,c0,c1
            float4 r2 = *(float4*)&sRec[k * 12 + 8];   // c2,pad,t,dt
            float t = r2.z, dt = r2.w;

            // ---- f/h hidden: one column per lane ----------------------
            float a = fmaf(t, wl1[0], b1w);
#pragma unroll
            for (int i = 0; i < 6; ++i) a = fmaf(z[i], wl1[1 + i], a);
            a = fmaf(r1.z, wl1[7], a);
            a = fmaf(r1.w, wl1[8], a);
            a = fmaf(r2.x, wl1[9], a);
            float hid = sp_f(a);

            float pp[6];
#pragma unroll
            for (int d = 0; d < 6; ++d) pp[d] = hid * wl2[d];
#pragma unroll
            for (int d = 0; d < 6; ++d) pp[d] += dpp_xor1(pp[d]);
#pragma unroll
            for (int d = 0; d < 6; ++d) pp[d] += dpp_xor2(pp[d]);
#pragma unroll
            for (int d = 0; d < 6; ++d) pp[d] += dpp_hmirror(pp[d]);
#pragma unroll
            for (int d = 0; d < 6; ++d) pp[d] += dpp_ror8(pp[d]);
#pragma unroll
            for (int d = 0; d < 6; ++d) pp[d] = xor16_sum(pp[d]);
            float fvv[6], dfh[6];
            bool lower = lane < 32;
#pragma unroll
            for (int d = 0; d < 6; ++d) {
                float oth = other_half(pp[d]);
                float fsum = lower ? pp[d] : oth;
                float hsum = lower ? oth : pp[d];
                fvv[d] = fsum + fb2v[d];
                dfh[d] = fvv[d] - (hsum + hb2v[d]);
            }
            if (lane == 0) {
                *(float4*)&exF[kb][0] = make_float4(fvv[0], fvv[1], fvv[2], fvv[3]);
                *(float4*)&exF[kb][4] = make_float4(fvv[4], fvv[5], dfh[0], dfh[1]);
                *(float4*)&exF[kb][8] = make_float4(dfh[2], dfh[3], dfh[4], dfh[5]);
            }

            __syncthreads();

            // ---- slim tail: own fvv regs + gl from LDS ----------------
            float4 g03 = *(float4*)&exG[kb][0];
            float2 g45 = *(float2*)&exG[kb][4];
            float gl[6] = { g03.x, g03.y, g03.z, g03.w, g45.x, g45.y };
            float dwv[6] = { r0.x, r0.y, r0.z, r0.w, r1.x, r1.y };
#pragma unroll
            for (int d = 0; d < 6; ++d)
                z[d] = fmaf(gl[d], dwv[d], fmaf(fvv[d], dt, z[d]));

            if (tid == 0) {
                float* zp = zsb + ((size_t)(k + 1) * Bn + b) * 6;
                *(float2*)(zp)     = make_float2(z[0], z[1]);
                *(float2*)(zp + 2) = make_float2(z[2], z[3]);
                *(float2*)(zp + 4) = make_float2(z[4], z[5]);
            }
        } else {
            float2 tdt = *(float2*)&sRec[k * 12 + 10];
            float t = tdt.x, dt = tdt.y;
            float dwq = sRec[k * 12 + dL];

            // ---- g hidden: 4 units/lane, 8-lane-group reduce ----------
            float ga = 0.f;
#pragma unroll
            for (int u = 0; u < 4; ++u) {
                float pre = fmaf(t, gwa[u], gbb[u]);
                pre = fmaf(zq, gwb[u], pre);
                ga = fmaf(sp_f(pre), gw2v[u], ga);
            }
            ga += dpp_xor1(ga);
            ga += dpp_xor2(ga);
            ga += dpp_hmirror(ga);
            float gacc = ga + gb2v;
            float e = __expf(-gacc);
            float rg = 1.f + e;                          // = 1/sigmoid
            float gval = __builtin_amdgcn_rcpf(rg);
            if ((lane & 7) == 0 && (lane >> 3) < 6)
                exG[kb][dL] = gval;

            __syncthreads();

            // ---- slim tail: own-dim only ------------------------------
            float fq  = exF[kb][dL];
            float dfq = exF[kb][6 + dL];
            float u = dfq * rg;
            pacc = fmaf(wselq * dt, u * u, pacc);
            zq = fmaf(gval, dwq, fmaf(fq, dt, zq));
        }
    }
    if (!isA) {
#pragma unroll
        for (int mm = 1; mm <= 32; mm <<= 1) pacc += __shfl_xor(pacc, mm);
        if (tid == 64) atomicAdd(&acc[2], pacc);
    }
}

// ------------------------------------------------------ decoder + likelihood
// M=2 samples/thread; LDS layout: dcW1 rows i*32 ; dcb1 @192 ;
// dcW2 rows 224+j1*32 ; dcb2 @1184 ; dcW3T rows 1216+j3*32 ; dcb3 @4416.
#define DEC_TLOAD(b0, b1, base)                                               \
    _Pragma("unroll")                                                         \
    for (int i = 0; i < 5; ++i) {                                             \
        b0[i] = *(const float2*)(tg0 + (base) + 2 * i);                       \
        b1[i] = *(const float2*)(tg1 + (base) + 2 * i);                       \
    }
#define DEC_LCOMP(b0, b1, base)                                               \
    _Pragma("unroll")                                                         \
    for (int i = 0; i < 10; ++i) {                                            \
        int ff = (base) + i;                                                  \
        float dma, dmb, dla, dlb;                                             \
        dot30_2(h2a, h2b, &w[1216 + ff * 32], dma, dmb);                      \
        dot30_2(h2a, h2b, &w[1216 + (50 + ff) * 32], dla, dlb);               \
        float xma = w[4416 + ff] + dma, xmb = w[4416 + ff] + dmb;             \
        float cla = clamp6(w[4416 + 50 + ff] + dla);                          \
        float clb = clamp6(w[4416 + 50 + ff] + dlb);                          \
        float tva = (i & 1) ? b0[i >> 1].y : b0[i >> 1].x;                    \
        float tvb = (i & 1) ? b1[i >> 1].y : b1[i >> 1].x;                    \
        float ua = (tva - xma) * __expf(-cla);                                \
        float ub = (tvb - xmb) * __expf(-clb);                                \
        lpa += -0.5f * ua * ua - cla - 0.91893853320467274f;                  \
        lpb += -0.5f * ub * ub - clb - 0.91893853320467274f;                  \
    }

__global__ __launch_bounds__(256) void dec_kernel(
    const float* __restrict__ zsb, const float* __restrict__ xs,
    const float* __restrict__ dcW1, const float* __restrict__ dcb1,
    const float* __restrict__ dcW2, const float* __restrict__ dcb2,
    const float* __restrict__ dcW3, const float* __restrict__ dcb3,
    float* __restrict__ acc)
{
    __shared__ float w[4516];
    for (int i = threadIdx.x; i < 180; i += 256) w[(i / 30) * 32 + (i % 30)] = dcW1[i];
    if (threadIdx.x < 30) w[192 + threadIdx.x] = dcb1[threadIdx.x];
    for (int i = threadIdx.x; i < 900; i += 256) w[224 + (i / 30) * 32 + (i % 30)] = dcW2[i];
    if (threadIdx.x < 30) w[1184 + threadIdx.x] = dcb2[threadIdx.x];
    for (int i = threadIdx.x; i < 3000; i += 256) {
        int j2 = i / 100, j3 = i % 100;
        w[1216 + j3 * 32 + j2] = dcW3[i];
    }
    for (int i = threadIdx.x; i < 100; i += 256) w[4416 + i] = dcb3[i];
    __syncthreads();

    int t = threadIdx.x;
    size_t base = (size_t)blockIdx.x * 512;
    size_t s0 = base + t, s1 = base + t + 256;

    float za[6], zb[6];
    {
        const float* zp0 = zsb + s0 * 6;
        const float* zp1 = zsb + s1 * 6;
#pragma unroll
        for (int i = 0; i < 3; ++i) {
            float2 v0 = *(const float2*)(zp0 + 2 * i);
            float2 v1 = *(const float2*)(zp1 + 2 * i);
            za[2 * i] = v0.x; za[2 * i + 1] = v0.y;
            zb[2 * i] = v1.x; zb[2 * i + 1] = v1.y;
        }
    }

    float h1a[30], h1b[30];
#pragma unroll
    for (int j = 0; j < 30; ++j) { h1a[j] = w[192 + j]; h1b[j] = h1a[j]; }
#pragma unroll
    for (int i = 0; i < 6; ++i) row2(h1a, h1b, &w[i * 32], za[i], zb[i]);
#pragma unroll
    for (int j = 0; j < 30; ++j) { h1a[j] = sp_f(h1a[j]); h1b[j] = sp_f(h1b[j]); }

    float h2a[30], h2b[30];
#pragma unroll
    for (int j = 0; j < 30; ++j) { h2a[j] = w[1184 + j]; h2b[j] = h2a[j]; }
#pragma unroll
    for (int j1 = 0; j1 < 30; ++j1)
        row2(h2a, h2b, &w[224 + j1 * 32], h1a[j1], h1b[j1]);
#pragma unroll
    for (int j = 0; j < 30; ++j) { h2a[j] = sp_f(h2a[j]); h2b[j] = sp_f(h2b[j]); }

    const float* tg0 = xs + s0 * 150 + 100;   // xs[:,:,-1,:]
    const float* tg1 = xs + s1 * 150 + 100;
    float lpa = 0.f, lpb = 0.f;
    float2 TA0[5], TA1[5], TB0[5], TB1[5];
    DEC_TLOAD(TA0, TA1, 0)
    DEC_TLOAD(TB0, TB1, 10)
    DEC_LCOMP(TA0, TA1, 0)
    DEC_TLOAD(TA0, TA1, 20)
    DEC_LCOMP(TB0, TB1, 10)
    DEC_TLOAD(TB0, TB1, 30)
    DEC_LCOMP(TA0, TA1, 20)
    DEC_TLOAD(TA0, TA1, 40)
    DEC_LCOMP(TB0, TB1, 30)
    DEC_LCOMP(TA0, TA1, 40)

    float lpacc = lpa + lpb;
#pragma unroll
    for (int mm = 1; mm <= 32; mm <<= 1) lpacc += __shfl_xor(lpacc, mm);
    __shared__ float red[4];
    if ((threadIdx.x & 63) == 0) red[threadIdx.x >> 6] = lpacc;
    __syncthreads();
    if (threadIdx.x == 0) atomicAdd(&acc[0], red[0] + red[1] + red[2] + red[3]);
}

__global__ void final_kernel(const float* __restrict__ acc, float* __restrict__ out)
{
    out[0] = acc[0] * (1.f / (float)Bn);
    out[1] = (acc[1] + acc[2]) * (1.f / (float)Bn);
}

// --------------------------------------------------------------------- launch
extern "C" void kernel_launch(void* const* d_in, const int* in_sizes, int n_in,
                              void* d_out, int out_size, void* d_ws, size_t ws_size,
                              hipStream_t stream)
{
    const float* xs   = (const float*)d_in[0];
    const float* ts   = (const float*)d_in[1];
    const float* eps0 = (const float*)d_in[2];
    const float* dW   = (const float*)d_in[3];
    const float* eW1  = (const float*)d_in[4];
    const float* eb1  = (const float*)d_in[5];
    const float* eW2  = (const float*)d_in[6];
    const float* eb2  = (const float*)d_in[7];
    const float* eW3  = (const float*)d_in[8];
    const float* eb3  = (const float*)d_in[9];
    const float* dcW1 = (const float*)d_in[10];
    const float* dcb1 = (const float*)d_in[11];
    const float* dcW2 = (const float*)d_in[12];
    const float* dcb2 = (const float*)d_in[13];
    const float* dcW3 = (const float*)d_in[14];
    const float* dcb3 = (const float*)d_in[15];
    const float* fW1  = (const float*)d_in[16];
    const float* fb1  = (const float*)d_in[17];
    const float* fW2  = (const float*)d_in[18];
    const float* fb2  = (const float*)d_in[19];
    const float* hW1  = (const float*)d_in[20];
    const float* hb1  = (const float*)d_in[21];
    const float* hW2  = (const float*)d_in[22];
    const float* hb2  = (const float*)d_in[23];
    const float* gW1  = (const float*)d_in[24];
    const float* gb1  = (const float*)d_in[25];
    const float* gW2  = (const float*)d_in[26];
    const float* gb2  = (const float*)d_in[27];
    const float* pm   = (const float*)d_in[28];
    const float* ps   = (const float*)d_in[29];

    float* ws  = (float*)d_ws;
    float* acc = ws;                    // [0]=S_lp, [1]=S_kl, [2]=S_path
    float* ctx = ws + 16;               // T*B*3 = 614400
    float* qm  = ctx + 614400;          // B*6
    float* qs  = qm + 12288;            // B*6
    float* zs  = qs + 12288;            // T*B*6 = 1228800
    float* out = (float*)d_out;

    hipMemsetAsync(acc, 0, 16 * sizeof(float), stream);
    enc_kernel<<<400, 256, 0, stream>>>(xs, eW1, eb1, eW2, eb2, eW3, eb3, ctx, qm, qs);
    scan_kernel<<<2048, 128, 0, stream>>>(ts, dW, fW1, fb1, fW2, fb2, hW1, hb1,
                                          hW2, hb2, gW1, gb1, gW2, gb2, ctx,
                                          qm, qs, eps0, pm, ps, zs, acc);
    dec_kernel<<<400, 256, 0, stream>>>(zs, xs, dcW1, dcb1, dcW2, dcb2, dcW3, dcb3, acc);
    final_kernel<<<1, 1, 0, stream>>>(acc, out);
}

// Round 12
// 243.882 us; speedup vs baseline: 1.2458x; 1.0394x over previous
//
#include <hip/hip_runtime.h>
#include <hip/hip_bf16.h>
#include <math.h>

#define Tn 100
#define Bn 2048

typedef int v2i __attribute__((ext_vector_type(2)));
typedef _Float16 h2v __attribute__((ext_vector_type(2)));

__device__ __forceinline__ float sp_f(float x) {
    // jax.nn.softplus(x) = max(x,0) + log1p(exp(-|x|))
    float e = __expf(-fabsf(x));
    return fmaxf(x, 0.f) + __logf(1.f + e);
}
__device__ __forceinline__ float clamp6(float x) {
    return fminf(fmaxf(x, -6.f), 6.f);
}
// pack two f32 into half2 (RNE via casts)
__device__ __forceinline__ unsigned int packh2(float a, float b) {
    h2v h; h.x = (_Float16)a; h.y = (_Float16)b;
    return __builtin_bit_cast(unsigned int, h);
}
// dot2: a.x*b.x + a.y*b.y + c  (f32 accumulate)
__device__ __forceinline__ float dot2f(unsigned int a, unsigned int b, float c) {
#if __has_builtin(__builtin_amdgcn_fdot2)
    return __builtin_amdgcn_fdot2(__builtin_bit_cast(h2v, a),
                                  __builtin_bit_cast(h2v, b), c, false);
#else
    h2v ha = __builtin_bit_cast(h2v, a), hb = __builtin_bit_cast(h2v, b);
    return fmaf((float)ha.y, (float)hb.y, fmaf((float)ha.x, (float)hb.x, c));
#endif
}

// DPP cross-lane (pure VALU).
__device__ __forceinline__ float dpp_xor1(float x) {
    return __int_as_float(__builtin_amdgcn_mov_dpp(__float_as_int(x), 0xB1, 0xF, 0xF, 1));
}
__device__ __forceinline__ float dpp_xor2(float x) {
    return __int_as_float(__builtin_amdgcn_mov_dpp(__float_as_int(x), 0x4E, 0xF, 0xF, 1));
}
__device__ __forceinline__ float dpp_hmirror(float x) {
    return __int_as_float(__builtin_amdgcn_mov_dpp(__float_as_int(x), 0x141, 0xF, 0xF, 1));
}
__device__ __forceinline__ float dpp_ror8(float x) {
    return __int_as_float(__builtin_amdgcn_mov_dpp(__float_as_int(x), 0x128, 0xF, 0xF, 1));
}
template <int OFF>
__device__ __forceinline__ float swz(float x) {
    return __int_as_float(__builtin_amdgcn_ds_swizzle(__float_as_int(x), OFF));
}
__device__ __forceinline__ float xor16_sum(float x) {
#if __has_builtin(__builtin_amdgcn_permlane16_swap)
    v2i r = __builtin_amdgcn_permlane16_swap(__float_as_int(x), __float_as_int(x), false, false);
    return __int_as_float(r[0]) + __int_as_float(r[1]);
#else
    return x + swz<0x401F>(x);
#endif
}
__device__ __forceinline__ float other_half(float x) {
#if __has_builtin(__builtin_amdgcn_permlane32_swap)
    v2i r = __builtin_amdgcn_permlane32_swap(__float_as_int(x), __float_as_int(x), false, false);
    return (__int_as_float(r[0]) + __int_as_float(r[1])) - x;
#else
    return __shfl_xor(x, 32);
#endif
}

// f16 pair-dot row: h{a,b}[0..29] = dot2(x{a,b}, wrow[j], h{a,b}[j])
__device__ __forceinline__ void rowd2(float* ha, float* hb, const unsigned int* wrow,
                                      unsigned int xa, unsigned int xb) {
#pragma unroll
    for (int q = 0; q < 7; ++q) {
        uint4 wv = *(const uint4*)(wrow + 4 * q);
        ha[4 * q + 0] = dot2f(xa, wv.x, ha[4 * q + 0]);
        hb[4 * q + 0] = dot2f(xb, wv.x, hb[4 * q + 0]);
        ha[4 * q + 1] = dot2f(xa, wv.y, ha[4 * q + 1]);
        hb[4 * q + 1] = dot2f(xb, wv.y, hb[4 * q + 1]);
        ha[4 * q + 2] = dot2f(xa, wv.z, ha[4 * q + 2]);
        hb[4 * q + 2] = dot2f(xb, wv.z, hb[4 * q + 2]);
        ha[4 * q + 3] = dot2f(xa, wv.w, ha[4 * q + 3]);
        hb[4 * q + 3] = dot2f(xb, wv.w, hb[4 * q + 3]);
    }
    uint2 wt = *(const uint2*)(wrow + 28);
    ha[28] = dot2f(xa, wt.x, ha[28]);
    hb[28] = dot2f(xb, wt.x, hb[28]);
    ha[29] = dot2f(xa, wt.y, ha[29]);
    hb[29] = dot2f(xb, wt.y, hb[29]);
}
// fp32 dual dot30 (for small fp32 layers)
__device__ __forceinline__ void dot30_2(const float* ha, const float* hb,
                                        const float* wrow, float& ra, float& rb) {
    float a0 = 0.f, a1 = 0.f, b0 = 0.f, b1 = 0.f;
#pragma unroll
    for (int q = 0; q < 7; ++q) {
        float4 wv = *(const float4*)(wrow + 4 * q);
        a0 = fmaf(ha[4 * q + 0], wv.x, a0);
        b0 = fmaf(hb[4 * q + 0], wv.x, b0);
        a1 = fmaf(ha[4 * q + 1], wv.y, a1);
        b1 = fmaf(hb[4 * q + 1], wv.y, b1);
        a0 = fmaf(ha[4 * q + 2], wv.z, a0);
        b0 = fmaf(hb[4 * q + 2], wv.z, b0);
        a1 = fmaf(ha[4 * q + 3], wv.w, a1);
        b1 = fmaf(hb[4 * q + 3], wv.w, b1);
    }
    float2 wt = *(const float2*)(wrow + 28);
    a0 = fmaf(ha[28], wt.x, a0);
    b0 = fmaf(hb[28], wt.x, b0);
    a1 = fmaf(ha[29], wt.y, a1);
    b1 = fmaf(hb[29], wt.y, b1);
    ra = a0 + a1; rb = b0 + b1;
}
// f16 16-pair dual dot (for dec L3; pair 15 must be zero)
__device__ __forceinline__ void dot16p_2(const unsigned int* pa, const unsigned int* pb,
                                         const unsigned int* wrow, float& ra, float& rb) {
    float a0 = 0.f, a1 = 0.f, b0 = 0.f, b1 = 0.f;
#pragma unroll
    for (int q = 0; q < 4; ++q) {
        uint4 wv = *(const uint4*)(wrow + 4 * q);
        a0 = dot2f(pa[4 * q + 0], wv.x, a0);
        b0 = dot2f(pb[4 * q + 0], wv.x, b0);
        a1 = dot2f(pa[4 * q + 1], wv.y, a1);
        b1 = dot2f(pb[4 * q + 1], wv.y, b1);
        a0 = dot2f(pa[4 * q + 2], wv.z, a0);
        b0 = dot2f(pb[4 * q + 2], wv.z, b0);
        a1 = dot2f(pa[4 * q + 3], wv.w, a1);
        b1 = dot2f(pb[4 * q + 3], wv.w, b1);
    }
    ra = a0 + a1; rb = b0 + b1;
}

// ---------------------------------------------------------------- encoder
// M=2 samples/thread. L1/L2 in packed f16 (pairs over input idx), L3 fp32.
// LDS: wh1[75][32] uint ; wh2[15][32] uint ;
// wf: eb1@0(30) eb2@30(30) wc3@60(3x32) wcq@156(12x32) eb3@540(15)
#define ENC_LOAD2(b0, b1, base)                                               \
    _Pragma("unroll")                                                         \
    for (int i = 0; i < 5; ++i) {                                             \
        b0[i] = *(const float2*)(x0 + (base) + 2 * i);                        \
        b1[i] = *(const float2*)(x1 + (base) + 2 * i);                        \
    }
#define ENC_COMP2(b0, b1, pb)                                                 \
    _Pragma("unroll")                                                         \
    for (int i = 0; i < 5; ++i) {                                             \
        unsigned int xa = packh2(b0[i].x, b0[i].y);                           \
        unsigned int xb = packh2(b1[i].x, b1[i].y);                           \
        rowd2(h1a, h1b, &wh1[((pb) + i) * 32], xa, xb);                       \
    }

__global__ __launch_bounds__(256) void enc_kernel(
    const float* __restrict__ xs,
    const float* __restrict__ eW1, const float* __restrict__ eb1,
    const float* __restrict__ eW2, const float* __restrict__ eb2,
    const float* __restrict__ eW3, const float* __restrict__ eb3,
    float* __restrict__ ctx, float* __restrict__ qm, float* __restrict__ qs)
{
    __shared__ __align__(16) unsigned int wh1[75 * 32];
    __shared__ __align__(16) unsigned int wh2[15 * 32];
    __shared__ __align__(16) float wf[555];

    for (int i = threadIdx.x; i < 75 * 30; i += 256) {
        int p = i / 30, j = i % 30;
        wh1[p * 32 + j] = packh2(eW1[(2 * p) * 30 + j], eW1[(2 * p + 1) * 30 + j]);
    }
    for (int i = threadIdx.x; i < 15 * 30; i += 256) {
        int p = i / 30, j = i % 30;
        wh2[p * 32 + j] = packh2(eW2[(2 * p) * 30 + j], eW2[(2 * p + 1) * 30 + j]);
    }
    if (threadIdx.x < 30) wf[threadIdx.x] = eb1[threadIdx.x];
    if (threadIdx.x >= 32 && threadIdx.x < 62) wf[30 + threadIdx.x - 32] = eb2[threadIdx.x - 32];
    for (int i = threadIdx.x; i < 90; i += 256) {        // wc3[o][j2] = eW3[j2][12+o]
        int o = i / 30, j2 = i % 30;
        wf[60 + o * 32 + j2] = eW3[j2 * 15 + 12 + o];
    }
    for (int i = threadIdx.x; i < 360; i += 256) {       // wcq[o][j2] = eW3[j2][o]
        int o = i / 30, j2 = i % 30;
        wf[156 + o * 32 + j2] = eW3[j2 * 15 + o];
    }
    if (threadIdx.x >= 64 && threadIdx.x < 79) wf[540 + threadIdx.x - 64] = eb3[threadIdx.x - 64];
    __syncthreads();

    int t = threadIdx.x;
    size_t base = (size_t)blockIdx.x * 512;
    size_t s0 = base + t, s1 = base + t + 256;
    const float* x0 = xs + s0 * 150;
    const float* x1 = xs + s1 * 150;

    float h1a[30], h1b[30];
#pragma unroll
    for (int j = 0; j < 30; ++j) { h1a[j] = wf[j]; h1b[j] = h1a[j]; }

    float2 A0[5], A1[5], B0[5], B1[5];
    ENC_LOAD2(A0, A1, 0)
    ENC_LOAD2(B0, B1, 10)
    int fb = 0;
#pragma unroll 1
    for (int it = 0; it < 6; ++it) {
        ENC_COMP2(A0, A1, fb / 2)
        ENC_LOAD2(A0, A1, fb + 20)
        ENC_COMP2(B0, B1, fb / 2 + 5)
        ENC_LOAD2(B0, B1, fb + 30)
        fb += 20;
    }
    ENC_COMP2(A0, A1, 60)
    ENC_LOAD2(A0, A1, 140)
    ENC_COMP2(B0, B1, 65)
    ENC_COMP2(A0, A1, 70)

#pragma unroll
    for (int j = 0; j < 30; ++j) { h1a[j] = sp_f(h1a[j]); h1b[j] = sp_f(h1b[j]); }

    // pack h1 pairs for L2
    unsigned int p1a[15], p1b[15];
#pragma unroll
    for (int p = 0; p < 15; ++p) {
        p1a[p] = packh2(h1a[2 * p], h1a[2 * p + 1]);
        p1b[p] = packh2(h1b[2 * p], h1b[2 * p + 1]);
    }
    float h2a[30], h2b[30];
#pragma unroll
    for (int j = 0; j < 30; ++j) { h2a[j] = wf[30 + j]; h2b[j] = h2a[j]; }
#pragma unroll
    for (int p = 0; p < 15; ++p)
        rowd2(h2a, h2b, &wh2[p * 32], p1a[p], p1b[p]);
#pragma unroll
    for (int j = 0; j < 30; ++j) { h2a[j] = sp_f(h2a[j]); h2b[j] = sp_f(h2b[j]); }

    // L3 ctx (fp32)
    float oa3[3], ob3[3];
#pragma unroll
    for (int o = 0; o < 3; ++o) {
        float ra, rb;
        dot30_2(h2a, h2b, &wf[60 + o * 32], ra, rb);
        oa3[o] = wf[540 + 12 + o] + ra;
        ob3[o] = wf[540 + 12 + o] + rb;
    }
    float* cp0 = ctx + s0 * 3;
    cp0[0] = oa3[0]; cp0[1] = oa3[1]; cp0[2] = oa3[2];
    float* cp1 = ctx + s1 * 3;
    cp1[0] = ob3[0]; cp1[1] = ob3[1]; cp1[2] = ob3[2];

    if (blockIdx.x < 4) {   // samples < 2048: tt == 0 -> qz0 stats (fp32)
#pragma unroll
        for (int o = 0; o < 12; ++o) {
            float ra, rb;
            dot30_2(h2a, h2b, &wf[156 + o * 32], ra, rb);
            float va = wf[540 + o] + ra, vb = wf[540 + o] + rb;
            if (o < 6) { qm[s0 * 6 + o] = va; qm[s1 * 6 + o] = vb; }
            else       { qs[s0 * 6 + o - 6] = va; qs[s1 * 6 + o - 6] = vb; }
        }
    }
}

// ------------------------------------------------------------------- SDE scan
// (unchanged from round 11: 2-wave asymmetric slim tails)
__global__ __launch_bounds__(128, 4) void scan_kernel(
    const float* __restrict__ ts, const float* __restrict__ dWall,
    const float* __restrict__ fW1, const float* __restrict__ fb1,
    const float* __restrict__ fW2, const float* __restrict__ fb2,
    const float* __restrict__ hW1, const float* __restrict__ hb1,
    const float* __restrict__ hW2, const float* __restrict__ hb2,
    const float* __restrict__ gW1, const float* __restrict__ gb1,
    const float* __restrict__ gW2, const float* __restrict__ gb2,
    const float* __restrict__ ctx,
    const float* __restrict__ qm, const float* __restrict__ qs,
    const float* __restrict__ eps0, const float* __restrict__ pm,
    const float* __restrict__ ps,
    float* __restrict__ zsb, float* __restrict__ acc)
{
    int tid = threadIdx.x;
    int lane = tid & 63;
    int b = blockIdx.x;
    bool isA = tid < 64;

    __shared__ float sRec[99 * 12];
    __shared__ float exF[2][12];      // [0..5]=fvv, [6..11]=dfh
    __shared__ float exG[2][8];       // [0..5]=g

    for (int i = tid; i < 99 * 3; i += 128) {
        int k = i / 3, e = i % 3;
        float2 v = *(const float2*)(dWall + ((size_t)k * Bn + b) * 6 + e * 2);
        *(float2*)&sRec[k * 12 + e * 2] = v;
    }
    for (int i = tid; i < 99 * 3; i += 128) {
        int k = i / 3, e = i % 3;
        sRec[k * 12 + 6 + e] = ctx[((size_t)(k + 1) * Bn + b) * 3 + e];
    }
    for (int i = tid; i < 99; i += 128) {
        float t0 = ts[i], t1 = ts[i + 1];
        sRec[i * 12 + 9]  = 0.f;
        sRec[i * 12 + 10] = t0;
        sRec[i * 12 + 11] = t1 - t0;
    }

    float z[6];
    float zq = 0.f;
    float wl1[10], b1w, wl2[6], fb2v[6], hb2v[6];
    float gwa[4], gwb[4], gw2v[4], gbb[4], gb2v = 0.f, wselq = 0.f;
    int dL = 0;

    if (isA) {
        bool lower = lane < 32;
        int j = lane & 31;
        int jc = (j < 30) ? j : 29;
        bool jvalid = (j < 30);
#pragma unroll
        for (int i = 0; i < 10; ++i)
            wl1[i] = lower ? fW1[i * 30 + jc] : (i < 7 ? hW1[i * 30 + jc] : 0.f);
        b1w = lower ? fb1[jc] : hb1[jc];
#pragma unroll
        for (int d = 0; d < 6; ++d)
            wl2[d] = jvalid ? (lower ? fW2[jc * 6 + d] : hW2[jc * 6 + d]) : 0.f;
#pragma unroll
        for (int d = 0; d < 6; ++d) { fb2v[d] = fb2[d]; hb2v[d] = hb2[d]; }
#pragma unroll
        for (int d = 0; d < 6; ++d) {
            float m = qm[b * 6 + d];
            float sq = __expf(clamp6(qs[b * 6 + d]));
            z[d] = fmaf(sq, eps0[b * 6 + d], m);
        }
        if (tid == 0) {
            float* zp = zsb + (size_t)b * 6;
            *(float2*)(zp)     = make_float2(z[0], z[1]);
            *(float2*)(zp + 2) = make_float2(z[2], z[3]);
            *(float2*)(zp + 4) = make_float2(z[4], z[5]);
        }
    } else {
        int dL8 = lane >> 3;
        dL = (dL8 < 6) ? dL8 : 0;
        wselq = (dL8 < 6) ? 0.0625f : 0.f;
        int s = lane & 7;
#pragma unroll
        for (int u = 0; u < 4; ++u) {
            int jj = s + 8 * u;
            bool ok = (dL8 < 6) && (jj < 30);
            gwa[u]  = ok ? gW1[dL * 60 + jj] : 0.f;
            gwb[u]  = ok ? gW1[dL * 60 + 30 + jj] : 0.f;
            gw2v[u] = ok ? gW2[dL * 30 + jj] : 0.f;
            gbb[u]  = ok ? gb1[dL * 30 + jj] : 0.f;
        }
        gb2v = gb2[dL];
        {
            float m = qm[b * 6 + dL];
            float sq = __expf(clamp6(qs[b * 6 + dL]));
            zq = fmaf(sq, eps0[b * 6 + dL], m);
        }
        if (tid == 64) {
            float klsum = 0.f;
#pragma unroll
            for (int d = 0; d < 6; ++d) {
                float m = qm[b * 6 + d];
                float sq = __expf(clamp6(qs[b * 6 + d]));
                float spz = __expf(clamp6(ps[d]));
                float dm = m - pm[d];
                klsum += __logf(spz / sq) + (sq * sq + dm * dm) / (2.f * spz * spz) - 0.5f;
            }
            atomicAdd(&acc[1], klsum);
        }
    }

    __syncthreads();

    float pacc = 0.f;

    for (int k = 0; k < Tn - 1; ++k) {
        int kb = k & 1;

        if (isA) {
            float4 r0 = *(float4*)&sRec[k * 12];
            float4 r1 = *(float4*)&sRec[k * 12 + 4];
            float4 r2 = *(float4*)&sRec[k * 12 + 8];
            float t = r2.z, dt = r2.w;

            float a = fmaf(t, wl1[0], b1w);
#pragma unroll
            for (int i = 0; i < 6; ++i) a = fmaf(z[i], wl1[1 + i], a);
            a = fmaf(r1.z, wl1[7], a);
            a = fmaf(r1.w, wl1[8], a);
            a = fmaf(r2.x, wl1[9], a);
            float hid = sp_f(a);

            float pp[6];
#pragma unroll
            for (int d = 0; d < 6; ++d) pp[d] = hid * wl2[d];
#pragma unroll
            for (int d = 0; d < 6; ++d) pp[d] += dpp_xor1(pp[d]);
#pragma unroll
            for (int d = 0; d < 6; ++d) pp[d] += dpp_xor2(pp[d]);
#pragma unroll
            for (int d = 0; d < 6; ++d) pp[d] += dpp_hmirror(pp[d]);
#pragma unroll
            for (int d = 0; d < 6; ++d) pp[d] += dpp_ror8(pp[d]);
#pragma unroll
            for (int d = 0; d < 6; ++d) pp[d] = xor16_sum(pp[d]);
            float fvv[6], dfh[6];
            bool lower = lane < 32;
#pragma unroll
            for (int d = 0; d < 6; ++d) {
                float oth = other_half(pp[d]);
                float fsum = lower ? pp[d] : oth;
                float hsum = lower ? oth : pp[d];
                fvv[d] = fsum + fb2v[d];
                dfh[d] = fvv[d] - (hsum + hb2v[d]);
            }
            if (lane == 0) {
                *(float4*)&exF[kb][0] = make_float4(fvv[0], fvv[1], fvv[2], fvv[3]);
                *(float4*)&exF[kb][4] = make_float4(fvv[4], fvv[5], dfh[0], dfh[1]);
                *(float4*)&exF[kb][8] = make_float4(dfh[2], dfh[3], dfh[4], dfh[5]);
            }

            __syncthreads();

            float4 g03 = *(float4*)&exG[kb][0];
            float2 g45 = *(float2*)&exG[kb][4];
            float gl[6] = { g03.x, g03.y, g03.z, g03.w, g45.x, g45.y };
            float dwv[6] = { r0.x, r0.y, r0.z, r0.w, r1.x, r1.y };
#pragma unroll
            for (int d = 0; d < 6; ++d)
                z[d] = fmaf(gl[d], dwv[d], fmaf(fvv[d], dt, z[d]));

            if (tid == 0) {
                float* zp = zsb + ((size_t)(k + 1) * Bn + b) * 6;
                *(float2*)(zp)     = make_float2(z[0], z[1]);
                *(float2*)(zp + 2) = make_float2(z[2], z[3]);
                *(float2*)(zp + 4) = make_float2(z[4], z[5]);
            }
        } else {
            float2 tdt = *(float2*)&sRec[k * 12 + 10];
            float t = tdt.x, dt = tdt.y;
            float dwq = sRec[k * 12 + dL];

            float ga = 0.f;
#pragma unroll
            for (int u = 0; u < 4; ++u) {
                float pre = fmaf(t, gwa[u], gbb[u]);
                pre = fmaf(zq, gwb[u], pre);
                ga = fmaf(sp_f(pre), gw2v[u], ga);
            }
            ga += dpp_xor1(ga);
            ga += dpp_xor2(ga);
            ga += dpp_hmirror(ga);
            float gacc = ga + gb2v;
            float e = __expf(-gacc);
            float rg = 1.f + e;
            float gval = __builtin_amdgcn_rcpf(rg);
            if ((lane & 7) == 0 && (lane >> 3) < 6)
                exG[kb][dL] = gval;

            __syncthreads();

            float fq  = exF[kb][dL];
            float dfq = exF[kb][6 + dL];
            float u = dfq * rg;
            pacc = fmaf(wselq * dt, u * u, pacc);
            zq = fmaf(gval, dwq, fmaf(fq, dt, zq));
        }
    }
    if (!isA) {
#pragma unroll
        for (int mm = 1; mm <= 32; mm <<= 1) pacc += __shfl_xor(pacc, mm);
        if (tid == 64) atomicAdd(&acc[2], pacc);
    }
}

// ------------------------------------------------------ decoder + likelihood
// M=2; L1 fp32, L2 f16-pairs, L3 f16-pairs (16-pair rows, pad 0).
// LDS: wd: dcW1 rows i*32 @0(192) ; dcb1 @192(30) ; dcb2 @224(30) ; dcb3 @256(100)
// wh2d[15][32] uint ; wh3[100][16] uint (dcW3T pairs, [ff][p])
#define DEC_TLOAD(b0, b1, base)                                               \
    _Pragma("unroll")                                                         \
    for (int i = 0; i < 5; ++i) {                                             \
        b0[i] = *(const float2*)(tg0 + (base) + 2 * i);                       \
        b1[i] = *(const float2*)(tg1 + (base) + 2 * i);                       \
    }
#define DEC_LCOMP(b0, b1, base)                                               \
    _Pragma("unroll")                                                         \
    for (int i = 0; i < 10; ++i) {                                            \
        int ff = (base) + i;                                                  \
        float dma, dmb, dla, dlb;                                             \
        dot16p_2(p2a, p2b, &wh3[ff * 16], dma, dmb);                          \
        dot16p_2(p2a, p2b, &wh3[(50 + ff) * 16], dla, dlb);                   \
        float xma = wd[256 + ff] + dma, xmb = wd[256 + ff] + dmb;             \
        float cla = clamp6(wd[256 + 50 + ff] + dla);                          \
        float clb = clamp6(wd[256 + 50 + ff] + dlb);                          \
        float tva = (i & 1) ? b0[i >> 1].y : b0[i >> 1].x;                    \
        float tvb = (i & 1) ? b1[i >> 1].y : b1[i >> 1].x;                    \
        float ua = (tva - xma) * __expf(-cla);                                \
        float ub = (tvb - xmb) * __expf(-clb);                                \
        lpa += -0.5f * ua * ua - cla - 0.91893853320467274f;                  \
        lpb += -0.5f * ub * ub - clb - 0.91893853320467274f;                  \
    }

__global__ __launch_bounds__(256) void dec_kernel(
    const float* __restrict__ zsb, const float* __restrict__ xs,
    const float* __restrict__ dcW1, const float* __restrict__ dcb1,
    const float* __restrict__ dcW2, const float* __restrict__ dcb2,
    const float* __restrict__ dcW3, const float* __restrict__ dcb3,
    float* __restrict__ acc)
{
    __shared__ __align__(16) float wd[356];
    __shared__ __align__(16) unsigned int wh2d[15 * 32];
    __shared__ __align__(16) unsigned int wh3[100 * 16];

    for (int i = threadIdx.x; i < 180; i += 256) wd[(i / 30) * 32 + (i % 30)] = dcW1[i];
    if (threadIdx.x < 30) wd[192 + threadIdx.x] = dcb1[threadIdx.x];
    if (threadIdx.x >= 32 && threadIdx.x < 62) wd[224 + threadIdx.x - 32] = dcb2[threadIdx.x - 32];
    for (int i = threadIdx.x; i < 100; i += 256) wd[256 + i] = dcb3[i];
    for (int i = threadIdx.x; i < 15 * 30; i += 256) {
        int p = i / 30, j = i % 30;
        wh2d[p * 32 + j] = packh2(dcW2[(2 * p) * 30 + j], dcW2[(2 * p + 1) * 30 + j]);
    }
    for (int i = threadIdx.x; i < 100 * 16; i += 256) {
        int ff = i / 16, p = i % 16;
        wh3[i] = (p < 15) ? packh2(dcW3[(2 * p) * 100 + ff], dcW3[(2 * p + 1) * 100 + ff]) : 0u;
    }
    __syncthreads();

    int t = threadIdx.x;
    size_t base = (size_t)blockIdx.x * 512;
    size_t s0 = base + t, s1 = base + t + 256;

    float za[6], zb[6];
    {
        const float* zp0 = zsb + s0 * 6;
        const float* zp1 = zsb + s1 * 6;
#pragma unroll
        for (int i = 0; i < 3; ++i) {
            float2 v0 = *(const float2*)(zp0 + 2 * i);
            float2 v1 = *(const float2*)(zp1 + 2 * i);
            za[2 * i] = v0.x; za[2 * i + 1] = v0.y;
            zb[2 * i] = v1.x; zb[2 * i + 1] = v1.y;
        }
    }

    float h1a[30], h1b[30];
#pragma unroll
    for (int j = 0; j < 30; ++j) { h1a[j] = wd[192 + j]; h1b[j] = h1a[j]; }
#pragma unroll
    for (int i = 0; i < 6; ++i) {
        float via = za[i], vib = zb[i];
        const float* wrow = &wd[i * 32];
#pragma unroll
        for (int q = 0; q < 7; ++q) {
            float4 wv = *(const float4*)(wrow + 4 * q);
            h1a[4 * q + 0] = fmaf(via, wv.x, h1a[4 * q + 0]);
            h1b[4 * q + 0] = fmaf(vib, wv.x, h1b[4 * q + 0]);
            h1a[4 * q + 1] = fmaf(via, wv.y, h1a[4 * q + 1]);
            h1b[4 * q + 1] = fmaf(vib, wv.y, h1b[4 * q + 1]);
            h1a[4 * q + 2] = fmaf(via, wv.z, h1a[4 * q + 2]);
            h1b[4 * q + 2] = fmaf(vib, wv.z, h1b[4 * q + 2]);
            h1a[4 * q + 3] = fmaf(via, wv.w, h1a[4 * q + 3]);
            h1b[4 * q + 3] = fmaf(vib, wv.w, h1b[4 * q + 3]);
        }
        float2 wt = *(const float2*)(wrow + 28);
        h1a[28] = fmaf(via, wt.x, h1a[28]);
        h1b[28] = fmaf(vib, wt.x, h1b[28]);
        h1a[29] = fmaf(via, wt.y, h1a[29]);
        h1b[29] = fmaf(vib, wt.y, h1b[29]);
    }
#pragma unroll
    for (int j = 0; j < 30; ++j) { h1a[j] = sp_f(h1a[j]); h1b[j] = sp_f(h1b[j]); }

    unsigned int p1a[15], p1b[15];
#pragma unroll
    for (int p = 0; p < 15; ++p) {
        p1a[p] = packh2(h1a[2 * p], h1a[2 * p + 1]);
        p1b[p] = packh2(h1b[2 * p], h1b[2 * p + 1]);
    }
    float h2a[30], h2b[30];
#pragma unroll
    for (int j = 0; j < 30; ++j) { h2a[j] = wd[224 + j]; h2b[j] = h2a[j]; }
#pragma unroll
    for (int p = 0; p < 15; ++p)
        rowd2(h2a, h2b, &wh2d[p * 32], p1a[p], p1b[p]);
#pragma unroll
    for (int j = 0; j < 30; ++j) { h2a[j] = sp_f(h2a[j]); h2b[j] = sp_f(h2b[j]); }

    unsigned int p2a[16], p2b[16];
#pragma unroll
    for (int p = 0; p < 15; ++p) {
        p2a[p] = packh2(h2a[2 * p], h2a[2 * p + 1]);
        p2b[p] = packh2(h2b[2 * p], h2b[2 * p + 1]);
    }
    p2a[15] = 0u; p2b[15] = 0u;

    const float* tg0 = xs + s0 * 150 + 100;   // xs[:,:,-1,:]
    const float* tg1 = xs + s1 * 150 + 100;
    float lpa = 0.f, lpb = 0.f;
    float2 TA0[5], TA1[5], TB0[5], TB1[5];
    DEC_TLOAD(TA0, TA1, 0)
    DEC_TLOAD(TB0, TB1, 10)
    DEC_LCOMP(TA0, TA1, 0)
    DEC_TLOAD(TA0, TA1, 20)
    DEC_LCOMP(TB0, TB1, 10)
    DEC_TLOAD(TB0, TB1, 30)
    DEC_LCOMP(TA0, TA1, 20)
    DEC_TLOAD(TA0, TA1, 40)
    DEC_LCOMP(TB0, TB1, 30)
    DEC_LCOMP(TA0, TA1, 40)

    float lpacc = lpa + lpb;
#pragma unroll
    for (int mm = 1; mm <= 32; mm <<= 1) lpacc += __shfl_xor(lpacc, mm);
    __shared__ float red[4];
    if ((threadIdx.x & 63) == 0) red[threadIdx.x >> 6] = lpacc;
    __syncthreads();
    if (threadIdx.x == 0) atomicAdd(&acc[0], red[0] + red[1] + red[2] + red[3]);
}

__global__ void final_kernel(const float* __restrict__ acc, float* __restrict__ out)
{
    out[0] = acc[0] * (1.f / (float)Bn);
    out[1] = (acc[1] + acc[2]) * (1.f / (float)Bn);
}

// --------------------------------------------------------------------- launch
extern "C" void kernel_launch(void* const* d_in, const int* in_sizes, int n_in,
                              void* d_out, int out_size, void* d_ws, size_t ws_size,
                              hipStream_t stream)
{
    const float* xs   = (const float*)d_in[0];
    const float* ts   = (const float*)d_in[1];
    const float* eps0 = (const float*)d_in[2];
    const float* dW   = (const float*)d_in[3];
    const float* eW1  = (const float*)d_in[4];
    const float* eb1  = (const float*)d_in[5];
    const float* eW2  = (const float*)d_in[6];
    const float* eb2  = (const float*)d_in[7];
    const float* eW3  = (const float*)d_in[8];
    const float* eb3  = (const float*)d_in[9];
    const float* dcW1 = (const float*)d_in[10];
    const float* dcb1 = (const float*)d_in[11];
    const float* dcW2 = (const float*)d_in[12];
    const float* dcb2 = (const float*)d_in[13];
    const float* dcW3 = (const float*)d_in[14];
    const float* dcb3 = (const float*)d_in[15];
    const float* fW1  = (const float*)d_in[16];
    const float* fb1  = (const float*)d_in[17];
    const float* fW2  = (const float*)d_in[18];
    const float* fb2  = (const float*)d_in[19];
    const float* hW1  = (const float*)d_in[20];
    const float* hb1  = (const float*)d_in[21];
    const float* hW2  = (const float*)d_in[22];
    const float* hb2  = (const float*)d_in[23];
    const float* gW1  = (const float*)d_in[24];
    const float* gb1  = (const float*)d_in[25];
    const float* gW2  = (const float*)d_in[26];
    const float* gb2  = (const float*)d_in[27];
    const float* pm   = (const float*)d_in[28];
    const float* ps   = (const float*)d_in[29];

    float* ws  = (float*)d_ws;
    float* acc = ws;                    // [0]=S_lp, [1]=S_kl, [2]=S_path
    float* ctx = ws + 16;               // T*B*3 = 614400
    float* qm  = ctx + 614400;          // B*6
    float* qs  = qm + 12288;            // B*6
    float* zs  = qs + 12288;            // T*B*6 = 1228800
    float* out = (float*)d_out;

    hipMemsetAsync(acc, 0, 16 * sizeof(float), stream);
    enc_kernel<<<400, 256, 0, stream>>>(xs, eW1, eb1, eW2, eb2, eW3, eb3, ctx, qm, qs);
    scan_kernel<<<2048, 128, 0, stream>>>(ts, dW, fW1, fb1, fW2, fb2, hW1, hb1,
                                          hW2, hb2, gW1, gb1, gW2, gb2, ctx,
                                          qm, qs, eps0, pm, ps, zs, acc);
    dec_kernel<<<400, 256, 0, stream>>>(zs, xs, dcW1, dcb1, dcW2, dcb2, dcW3, dcb3, acc);
    final_kernel<<<1, 1, 0, stream>>>(acc, out);
}